// Round 5
// baseline (183.100 us; speedup 1.0000x reference)
//
#include <hip/hip_runtime.h>
#include <math.h>

#define CHUNK 32   // rows per chunk; NC = T/CHUNK = 48 for T=1536

__device__ __forceinline__ float agent_load_f(const float* p) {
    return __hip_atomic_load(p, __ATOMIC_RELAXED, __HIP_MEMORY_SCOPE_AGENT);
}
__device__ __forceinline__ void agent_store_f(float* p, float v) {
    __hip_atomic_store(p, v, __ATOMIC_RELAXED, __HIP_MEMORY_SCOPE_AGENT);
}

// ---------------- K1: projections, W read from HBM exactly once ----------------
// grid (D)=128 blocks, 512 threads. Block d stages Wq/Wk/Wv row d in LDS (48 KB),
// then each of 8 waves computes q/k/v[d] for 4 batches. Also zeroes the flags.
__global__ void proj_kernel(const float* __restrict__ x,
                            const float* __restrict__ Wq,
                            const float* __restrict__ Wk,
                            const float* __restrict__ Wv,
                            float* __restrict__ qkv,   // [3][B][D]
                            int* __restrict__ flags, int nflags,
                            int B, int E, int D)
{
    int d = blockIdx.x;
    int tid = threadIdx.x;   // 0..511
    int wave = tid >> 6;     // 0..7
    int lane = tid & 63;
    extern __shared__ float wsh[];   // 3*E floats

    if (d == 0) {
        for (int i = tid; i < nflags; i += blockDim.x) flags[i] = 0;
    }

    const float4* srcq = (const float4*)(Wq + (size_t)d * E);
    const float4* srck = (const float4*)(Wk + (size_t)d * E);
    const float4* srcv = (const float4*)(Wv + (size_t)d * E);
    float4* w4 = (float4*)wsh;
    int E4 = E >> 2;                 // 1024
    for (int i = tid; i < E4; i += blockDim.x) {
        w4[i]          = srcq[i];
        w4[E4 + i]     = srck[i];
        w4[2*E4 + i]   = srcv[i];
    }
    __syncthreads();

    int b0 = wave * 4;               // 8 waves x 4 batches = 32
    const float4* x0 = (const float4*)(x + (size_t)(b0 + 0) * E);
    const float4* x1 = (const float4*)(x + (size_t)(b0 + 1) * E);
    const float4* x2 = (const float4*)(x + (size_t)(b0 + 2) * E);
    const float4* x3 = (const float4*)(x + (size_t)(b0 + 3) * E);

    float aq[4] = {0,0,0,0}, ak[4] = {0,0,0,0}, av[4] = {0,0,0,0};
    int iters = E4 >> 6;             // 16
    for (int ii = 0; ii < iters; ++ii) {
        int i4 = ii * 64 + lane;     // lane-contiguous: coalesced + conflict-free
        float4 qv = w4[i4];
        float4 kv_ = w4[E4 + i4];
        float4 vv = w4[2*E4 + i4];
        float4 xa = x0[i4], xb = x1[i4], xc = x2[i4], xd = x3[i4];
        aq[0] += xa.x*qv.x + xa.y*qv.y + xa.z*qv.z + xa.w*qv.w;
        ak[0] += xa.x*kv_.x + xa.y*kv_.y + xa.z*kv_.z + xa.w*kv_.w;
        av[0] += xa.x*vv.x + xa.y*vv.y + xa.z*vv.z + xa.w*vv.w;
        aq[1] += xb.x*qv.x + xb.y*qv.y + xb.z*qv.z + xb.w*qv.w;
        ak[1] += xb.x*kv_.x + xb.y*kv_.y + xb.z*kv_.z + xb.w*kv_.w;
        av[1] += xb.x*vv.x + xb.y*vv.y + xb.z*vv.z + xb.w*vv.w;
        aq[2] += xc.x*qv.x + xc.y*qv.y + xc.z*qv.z + xc.w*qv.w;
        ak[2] += xc.x*kv_.x + xc.y*kv_.y + xc.z*kv_.z + xc.w*kv_.w;
        av[2] += xc.x*vv.x + xc.y*vv.y + xc.z*vv.z + xc.w*vv.w;
        aq[3] += xd.x*qv.x + xd.y*qv.y + xd.z*qv.z + xd.w*qv.w;
        ak[3] += xd.x*kv_.x + xd.y*kv_.y + xd.z*kv_.z + xd.w*kv_.w;
        av[3] += xd.x*vv.x + xd.y*vv.y + xd.z*vv.z + xd.w*vv.w;
    }
    #pragma unroll
    for (int u = 0; u < 4; ++u) {
        #pragma unroll
        for (int off = 32; off >= 1; off >>= 1) {
            aq[u] += __shfl_xor(aq[u], off, 64);
            ak[u] += __shfl_xor(ak[u], off, 64);
            av[u] += __shfl_xor(av[u], off, 64);
        }
    }
    if (lane == 0) {
        #pragma unroll
        for (int u = 0; u < 4; ++u) {
            int b = b0 + u;
            qkv[(size_t)b * D + d]            = aq[u];
            qkv[((size_t)B + b) * D + d]      = ak[u];
            qkv[((size_t)2 * B + b) * D + d]  = av[u];
        }
    }
}

// ---------------- K2: fused scores + partials + decoupled lookback + output ----
// grid (B*NC) 1-D, bid = b*NC + c (c ascending => predecessors dispatched first).
// No max-subtraction: |s| <= ~20 at these input scales, exp(s) is fp32-safe, so
// cross-chunk combine is a plain order-independent SUM -> lookback works.
__global__ void __launch_bounds__(256)
fused_attn_kernel(const float* __restrict__ kv,     // [2][B][MT][D]
                  const float* __restrict__ qkv,    // [3][B][D]
                  const int* __restrict__ next_pos,
                  float* __restrict__ accpub,       // [B*NC][D]
                  float* __restrict__ lpub,         // [B*NC]
                  int* __restrict__ flags,          // [B*NC]
                  float* __restrict__ out,          // [B][T][D]
                  int B, int D, int T, int MT, int NC, float scale)
{
    int bid = blockIdx.x;
    int b = bid / NC;
    int c = bid - b * NC;
    int tid = threadIdx.x;   // 0..255
    int wave = tid >> 6, lane = tid & 63;
    int l16 = lane & 15, g16 = lane >> 4;

    __shared__ float vs[CHUNK * 128];   // 16 KB staged v rows (reused twice)
    __shared__ float w_sh[CHUNK];
    __shared__ float rl_sh[CHUNK];
    __shared__ float Lc_sh;

    int np = next_pos[b];
    int t0 = c * CHUNK;
    const float* q     = qkv + (size_t)b * D;
    const float* knew  = qkv + ((size_t)B + b) * D;
    const float* kbase = kv + (size_t)b * MT * D;
    const float4* vnew4  = (const float4*)(qkv + ((size_t)2 * B + b) * D);
    const float4* vbase4 = (const float4*)(kv + ((size_t)B + b) * MT * D);

    // ---- issue all global loads up front ----
    float4 qa = *(const float4*)(q + l16 * 8);
    float4 qb = *(const float4*)(q + l16 * 8 + 4);

    int j0 = wave * 8 + g16, j1 = j0 + 4;
    int ta = t0 + j0, tb = t0 + j1;
    const float* kra = (ta == np) ? knew : (kbase + (size_t)ta * D);
    const float* krb = (tb == np) ? knew : (kbase + (size_t)tb * D);
    float4 ka0 = *(const float4*)(kra + l16 * 8);
    float4 kb0 = *(const float4*)(kra + l16 * 8 + 4);
    float4 ka1 = *(const float4*)(krb + l16 * 8);
    float4 kb1 = *(const float4*)(krb + l16 * 8 + 4);

    float4 sv0, sv1, sv2, sv3;
    {
        int i4, t;
        i4 = tid;       t = t0 + (i4 >> 5);
        sv0 = (t == np) ? vnew4[i4 & 31] : vbase4[(size_t)t * 32 + (i4 & 31)];
        i4 = tid + 256; t = t0 + (i4 >> 5);
        sv1 = (t == np) ? vnew4[i4 & 31] : vbase4[(size_t)t * 32 + (i4 & 31)];
        i4 = tid + 512; t = t0 + (i4 >> 5);
        sv2 = (t == np) ? vnew4[i4 & 31] : vbase4[(size_t)t * 32 + (i4 & 31)];
        i4 = tid + 768; t = t0 + (i4 >> 5);
        sv3 = (t == np) ? vnew4[i4 & 31] : vbase4[(size_t)t * 32 + (i4 & 31)];
    }

    // ---- scores -> w = exp(s*scale), no max subtraction ----
    {
        float ps = qa.x*ka0.x + qa.y*ka0.y + qa.z*ka0.z + qa.w*ka0.w
                 + qb.x*kb0.x + qb.y*kb0.y + qb.z*kb0.z + qb.w*kb0.w;
        ps += __shfl_xor(ps, 1, 64);
        ps += __shfl_xor(ps, 2, 64);
        ps += __shfl_xor(ps, 4, 64);
        ps += __shfl_xor(ps, 8, 64);
        if (l16 == 0) w_sh[j0] = __expf(ps * scale);

        float pt = qa.x*ka1.x + qa.y*ka1.y + qa.z*ka1.z + qa.w*ka1.w
                 + qb.x*kb1.x + qb.y*kb1.y + qb.z*kb1.z + qb.w*kb1.w;
        pt += __shfl_xor(pt, 1, 64);
        pt += __shfl_xor(pt, 2, 64);
        pt += __shfl_xor(pt, 4, 64);
        pt += __shfl_xor(pt, 8, 64);
        if (l16 == 0) w_sh[j1] = __expf(pt * scale);
    }
    ((float4*)vs)[tid]       = sv0;
    ((float4*)vs)[tid + 256] = sv1;
    ((float4*)vs)[tid + 512] = sv2;
    ((float4*)vs)[tid + 768] = sv3;
    __syncthreads();

    // ---- chunk partial sums, publish with agent scope (bypasses per-XCD L2) ----
    if (tid < 128) {
        float a = 0.f;
        #pragma unroll
        for (int j = 0; j < CHUNK; ++j)
            a += w_sh[j] * vs[j * 128 + tid];
        agent_store_f(accpub + (size_t)bid * 128 + tid, a);
    } else if (tid < 192) {          // wave 2: chunk weight sum
        int j = tid - 128;           // 0..63
        float lw = (j < CHUNK) ? w_sh[j] : 0.f;
        #pragma unroll
        for (int off = 32; off >= 1; off >>= 1)
            lw += __shfl_xor(lw, off, 64);
        if (j == 0) agent_store_f(lpub + bid, lw);
    }
    __syncthreads();                 // every thread's stores are vmcnt-drained
    if (tid == 0)
        __hip_atomic_store(flags + bid, 1, __ATOMIC_RELEASE, __HIP_MEMORY_SCOPE_AGENT);

    // ---- decoupled lookback over predecessors (sum; order-independent) ----
    if (tid < 64 && tid < c) {       // c <= 47 < 64: all flags checked by wave 0
        const int* fp = flags + b * NC + tid;
        while (__hip_atomic_load(fp, __ATOMIC_RELAXED, __HIP_MEMORY_SCOPE_AGENT) == 0)
            __builtin_amdgcn_s_sleep(2);
    }
    __syncthreads();

    float A = 0.f;
    if (tid < 128) {
        const float* ap = accpub + (size_t)(b * NC) * 128 + tid;
        #pragma unroll 8
        for (int cc = 0; cc < c; ++cc)
            A += agent_load_f(ap + (size_t)cc * 128);
    } else if (tid < 192) {          // wave 2: carry denominator
        int cc = tid - 128;
        float lv = (cc < c) ? agent_load_f(lpub + b * NC + cc) : 0.f;
        #pragma unroll
        for (int off = 32; off >= 1; off >>= 1)
            lv += __shfl_xor(lv, off, 64);
        if (cc == 0) Lc_sh = lv;
    }
    __syncthreads();

    // ---- per-row reciprocal denominators via 32-lane prefix scan ----
    if (tid < CHUNK) {
        float wv = w_sh[tid];
        float xacc = wv;
        #pragma unroll
        for (int off = 1; off < 32; off <<= 1) {
            float n = __shfl_up(xacc, off, 64);
            if (tid >= off) xacc += n;
        }
        rl_sh[tid] = 1.0f / (Lc_sh + xacc);
    }
    __syncthreads();

    // ---- prefix stream from LDS, coalesced stores ----
    if (tid < 128) {
        float* orow = out + ((size_t)b * T + t0) * (size_t)D + tid;
        #pragma unroll
        for (int j = 0; j < CHUNK; ++j) {
            A += w_sh[j] * vs[j * 128 + tid];
            orow[(size_t)j * D] = A * rl_sh[j];
        }
    }
}

extern "C" void kernel_launch(void* const* d_in, const int* in_sizes, int n_in,
                              void* d_out, int out_size, void* d_ws, size_t ws_size,
                              hipStream_t stream) {
    const float* x        = (const float*)d_in[0];
    const float* Wq       = (const float*)d_in[1];
    const float* Wk       = (const float*)d_in[2];
    const float* Wv       = (const float*)d_in[3];
    const float* kv       = (const float*)d_in[4];
    const int*   next_pos = (const int*)d_in[5];
    float* out = (float*)d_out;

    const int B  = in_sizes[5];                 // 32
    const int E  = in_sizes[0] / B;             // 4096
    const int D  = in_sizes[1] / E;             // 128
    const int T  = out_size / (B * D);          // 1536
    const int MT = in_sizes[4] / (2 * B * D);   // 2048
    const int NC = T / CHUNK;                   // 48 (T is an exact multiple)

    float* ws     = (float*)d_ws;
    float* qkv    = ws;                                   // 3*B*D
    float* accpub = qkv + (size_t)3 * B * D;              // B*NC*D
    float* lpub   = accpub + (size_t)B * NC * D;          // B*NC
    int*   flags  = (int*)(lpub + (size_t)B * NC);        // B*NC

    const float scale = 1.0f / sqrtf((float)D);

    proj_kernel<<<dim3(D), 512, (size_t)3 * E * sizeof(float), stream>>>(
        x, Wq, Wk, Wv, qkv, flags, B * NC, B, E, D);
    fused_attn_kernel<<<dim3(B * NC), 256, 0, stream>>>(
        kv, qkv, next_pos, accpub, lpub, flags, out,
        B, D, T, MT, NC, scale);
}

// Round 6
// 135.252 us; speedup vs baseline: 1.3538x; 1.3538x over previous
//
#include <hip/hip_runtime.h>
#include <math.h>

#define CHUNK 32   // rows per chunk; NC = T/32 = 48 for T=1536

// ---------------- K1: fused q/k/v projections ----------------
// grid (D, B), block 64. One wave computes q[d],k[d],v[d] for batch b.
__global__ void proj_kernel(const float* __restrict__ x,
                            const float* __restrict__ Wq,
                            const float* __restrict__ Wk,
                            const float* __restrict__ Wv,
                            float* __restrict__ qkv, // [3][B][D]
                            int B, int E, int D)
{
    int d = blockIdx.x;
    int b = blockIdx.y;
    int lane = threadIdx.x; // 0..63
    const float* xrow = x + (size_t)b * E;
    size_t woff = (size_t)d * E;
    float aq = 0.f, ak = 0.f, av = 0.f;
    int iters = E >> 8;                       // 16 at E=4096
    #pragma unroll 4
    for (int it = 0; it < iters; ++it) {
        int i = lane * 4 + it * 256;
        float4 x4 = *(const float4*)(xrow + i);
        float4 q4 = *(const float4*)(Wq + woff + i);
        float4 k4 = *(const float4*)(Wk + woff + i);
        float4 v4 = *(const float4*)(Wv + woff + i);
        aq += x4.x*q4.x + x4.y*q4.y + x4.z*q4.z + x4.w*q4.w;
        ak += x4.x*k4.x + x4.y*k4.y + x4.z*k4.z + x4.w*k4.w;
        av += x4.x*v4.x + x4.y*v4.y + x4.z*v4.z + x4.w*v4.w;
    }
    #pragma unroll
    for (int off = 32; off >= 1; off >>= 1) {
        aq += __shfl_xor(aq, off, 64);
        ak += __shfl_xor(ak, off, 64);
        av += __shfl_xor(av, off, 64);
    }
    if (lane == 0) {
        qkv[(size_t)b * D + d] = aq;
        qkv[((size_t)B + b) * D + d] = ak;
        qkv[((size_t)2 * B + b) * D + d] = av;
    }
}

// ---------------- K2: scores + per-chunk online-softmax partials ----------------
// grid (NC, B), block 256. ALL global loads issued before any dependent compute.
__global__ void score_chunk_kernel(const float* __restrict__ kv,  // [2][B][MT][D]
                                   const float* __restrict__ qkv, // [3][B][D]
                                   const int* __restrict__ next_pos,
                                   float* __restrict__ w_out,     // [B][T] exp(s-m_c)
                                   float* __restrict__ m_out,     // [B][NC]
                                   float* __restrict__ l_out,     // [B][NC]
                                   float* __restrict__ acc_out,   // [B][NC][D]
                                   int B, int D, int T, int MT, int NC, float scale)
{
    int c = blockIdx.x;
    int b = blockIdx.y;
    int tid = threadIdx.x;   // 0..255
    int wave = tid >> 6;
    int lane = tid & 63;
    int l16 = lane & 15;     // position within 16-lane row group
    int g16 = lane >> 4;     // row group 0..3 within wave

    __shared__ float s_sh[CHUNK];
    __shared__ float w_sh[CHUNK];
    __shared__ float part[8][128];

    int np = next_pos[b];
    int t0 = c * CHUNK;
    const float* q    = qkv + (size_t)b * D;
    const float* knew = qkv + ((size_t)B + b) * D;
    const float* kbase = kv + (size_t)b * MT * D;
    const float4* vnew4 = (const float4*)(qkv + ((size_t)2 * B + b) * D);
    const float4* vbase4 = (const float4*)(kv + ((size_t)B + b) * MT * D);

    // ---- issue ALL global loads up front (one round trip) ----
    float4 qa = *(const float4*)(q + l16 * 8);
    float4 qb = *(const float4*)(q + l16 * 8 + 4);

    int j0 = wave * 8 + g16;         // score row, pass 0
    int j1 = wave * 8 + 4 + g16;     // score row, pass 1
    int ta = t0 + j0, tb = t0 + j1;
    const float* krowa = (ta == np) ? knew : (kbase + (size_t)ta * D);
    const float* krowb = (tb == np) ? knew : (kbase + (size_t)tb * D);
    float4 ka0 = *(const float4*)(krowa + l16 * 8);
    float4 kb0 = *(const float4*)(krowa + l16 * 8 + 4);
    float4 ka1 = *(const float4*)(krowb + l16 * 8);
    float4 kb1 = *(const float4*)(krowb + l16 * 8 + 4);

    int rg = tid >> 5;       // 0..7 (4 v-rows each)
    int d4 = tid & 31;       // float4 column
    float4 v0, v1, v2, v3;
    {
        int t;
        t = t0 + rg * 4 + 0; v0 = (t == np) ? vnew4[d4] : vbase4[(size_t)t * 32 + d4];
        t = t0 + rg * 4 + 1; v1 = (t == np) ? vnew4[d4] : vbase4[(size_t)t * 32 + d4];
        t = t0 + rg * 4 + 2; v2 = (t == np) ? vnew4[d4] : vbase4[(size_t)t * 32 + d4];
        t = t0 + rg * 4 + 3; v3 = (t == np) ? vnew4[d4] : vbase4[(size_t)t * 32 + d4];
    }

    // ---- scores ----
    {
        float ps = qa.x*ka0.x + qa.y*ka0.y + qa.z*ka0.z + qa.w*ka0.w
                 + qb.x*kb0.x + qb.y*kb0.y + qb.z*kb0.z + qb.w*kb0.w;
        ps += __shfl_xor(ps, 1, 64);
        ps += __shfl_xor(ps, 2, 64);
        ps += __shfl_xor(ps, 4, 64);
        ps += __shfl_xor(ps, 8, 64);
        if (l16 == 0) s_sh[j0] = (ta < T) ? ps * scale : -1e30f;

        float pt = qa.x*ka1.x + qa.y*ka1.y + qa.z*ka1.z + qa.w*ka1.w
                 + qb.x*kb1.x + qb.y*kb1.y + qb.z*kb1.z + qb.w*kb1.w;
        pt += __shfl_xor(pt, 1, 64);
        pt += __shfl_xor(pt, 2, 64);
        pt += __shfl_xor(pt, 4, 64);
        pt += __shfl_xor(pt, 8, 64);
        if (l16 == 0) s_sh[j1] = (tb < T) ? pt * scale : -1e30f;
    }
    __syncthreads();

    // wave 0: chunk max, weights, weight-sum; store w to global
    if (wave == 0) {
        float sv = s_sh[lane & 31];
        float m = sv;
        #pragma unroll
        for (int off = 16; off >= 1; off >>= 1)
            m = fmaxf(m, __shfl_xor(m, off, 64));
        float w = __expf(sv - m);
        w_sh[lane & 31] = w;
        float l = w;
        #pragma unroll
        for (int off = 16; off >= 1; off >>= 1)
            l += __shfl_xor(l, off, 64);
        if (lane < 32 && t0 + lane < T)
            w_out[(size_t)b * T + t0 + lane] = w;
        if (lane == 0) {
            m_out[(size_t)b * NC + c] = m;
            l_out[(size_t)b * NC + c] = l;
        }
    }
    __syncthreads();

    // v accumulation from registers
    {
        float w0 = w_sh[rg * 4 + 0], w1 = w_sh[rg * 4 + 1];
        float w2 = w_sh[rg * 4 + 2], w3 = w_sh[rg * 4 + 3];
        float4 a4;
        a4.x = w0*v0.x + w1*v1.x + w2*v2.x + w3*v3.x;
        a4.y = w0*v0.y + w1*v1.y + w2*v2.y + w3*v3.y;
        a4.z = w0*v0.z + w1*v1.z + w2*v2.z + w3*v3.z;
        a4.w = w0*v0.w + w1*v1.w + w2*v2.w + w3*v3.w;
        ((float4*)&part[rg][d4 * 4])[0] = a4;
    }
    __syncthreads();
    if (tid < 128) {
        float s = 0.f;
        #pragma unroll
        for (int r = 0; r < 8; ++r) s += part[r][tid];
        acc_out[((size_t)b * NC + c) * D + tid] = s;
    }
}

// ---------------- K2b: cross-chunk online-softmax scan ----------------
// grid (B), block 128 (thread = d). Emits exclusive carries per chunk.
__global__ void scan_kernel(const float* __restrict__ m_in,   // [B][NC]
                            const float* __restrict__ l_in,   // [B][NC]
                            const float* __restrict__ acc_in, // [B][NC][D]
                            float* __restrict__ Mc_out,       // [B][NC] running max
                            float* __restrict__ carryL_out,   // [B][NC]
                            float* __restrict__ carryA_out,   // [B][NC][D]
                            int B, int D, int NC)
{
    int b = blockIdx.x;
    int tid = threadIdx.x; // 0..127 = d

    extern __shared__ float sh[];            // accs[NC*128] + m_l[NC] + l_l[NC]
    float* accs = sh;
    float* m_l  = sh + (size_t)NC * 128;
    float* l_l  = m_l + NC;

    const float4* asrc = (const float4*)(acc_in + (size_t)b * NC * D);
    float4* adst = (float4*)accs;
    for (int i = tid; i < NC * 32; i += 128)
        adst[i] = asrc[i];
    if (tid < NC) {
        m_l[tid] = m_in[(size_t)b * NC + tid];
        l_l[tid] = l_in[(size_t)b * NC + tid];
    }
    __syncthreads();

    float M = -1e30f, A = 0.f, L = 0.f;
    float* caout = carryA_out + (size_t)b * NC * D + tid;
    float a_next = accs[tid];
    for (int c = 0; c < NC; ++c) {
        float a_c = a_next;
        if (c + 1 < NC) a_next = accs[(c + 1) * 128 + tid];  // prefetch
        float mc = m_l[c];
        float Mn = fmaxf(M, mc);
        float e_old = __expf(M - Mn);
        float Ac = A * e_old;                 // exclusive carry numerator
        caout[(size_t)c * D] = Ac;
        if (tid == 0) {
            Mc_out[(size_t)b * NC + c] = Mn;
            carryL_out[(size_t)b * NC + c] = L * e_old;
        }
        float e_c = __expf(mc - Mn);
        A = Ac + e_c * a_c;
        L = L * e_old + e_c * l_l[c];
        M = Mn;
    }
}

// ---------------- K3: per-chunk prefix outputs ----------------
// grid (NC, B), block 256. All loads issued up front; shuffle prefix-scan.
__global__ void out_kernel(const float* __restrict__ kv,
                           const float* __restrict__ qkv,
                           const int* __restrict__ next_pos,
                           const float* __restrict__ w_in,     // [B][T]
                           const float* __restrict__ m_in,     // [B][NC]
                           const float* __restrict__ Mc_in,    // [B][NC]
                           const float* __restrict__ carryL_in,// [B][NC]
                           const float* __restrict__ carryA_in,// [B][NC][D]
                           float* __restrict__ out,            // [B][T][D]
                           int B, int D, int T, int MT, int NC)
{
    int c = blockIdx.x;
    int b = blockIdx.y;
    int tid = threadIdx.x; // 0..255

    __shared__ float vs[CHUNK * 128];  // 16 KB staged v rows
    __shared__ float w_sh[CHUNK];
    __shared__ float rl_sh[CHUNK];

    int np = next_pos[b];
    int t0 = c * CHUNK;

    const float4* vnew4 = (const float4*)(qkv + ((size_t)2 * B + b) * D);
    const float4* vbase4 = (const float4*)(kv + ((size_t)B + b) * MT * D);

    // ---- issue all loads up front ----
    // stage v: all 256 threads, 4 float4 each (contiguous slots)
    float4 sv0, sv1, sv2, sv3;
    {
        int i4, t;
        i4 = tid;       t = t0 + (i4 >> 5);
        sv0 = (t == np) ? vnew4[i4 & 31] : vbase4[(size_t)t * 32 + (i4 & 31)];
        i4 = tid + 256; t = t0 + (i4 >> 5);
        sv1 = (t == np) ? vnew4[i4 & 31] : vbase4[(size_t)t * 32 + (i4 & 31)];
        i4 = tid + 512; t = t0 + (i4 >> 5);
        sv2 = (t == np) ? vnew4[i4 & 31] : vbase4[(size_t)t * 32 + (i4 & 31)];
        i4 = tid + 768; t = t0 + (i4 >> 5);
        sv3 = (t == np) ? vnew4[i4 & 31] : vbase4[(size_t)t * 32 + (i4 & 31)];
    }
    float A = 0.f;
    if (tid < 128)
        A = carryA_in[((size_t)b * NC + c) * D + tid];   // one coalesced read
    float wv = 0.f;
    float f = 0.f;
    if (tid < CHUNK) {
        int t = t0 + tid;
        f = __expf(m_in[(size_t)b * NC + c] - Mc_in[(size_t)b * NC + c]);
        wv = (t < T) ? w_in[(size_t)b * T + t] * f : 0.f;
    }

    ((float4*)vs)[tid]       = sv0;
    ((float4*)vs)[tid + 256] = sv1;
    ((float4*)vs)[tid + 512] = sv2;
    ((float4*)vs)[tid + 768] = sv3;
    if (tid < CHUNK) {
        w_sh[tid] = wv;
        // inclusive prefix-sum of w over 32 lanes (5 shuffle steps)
        float xacc = wv;
        #pragma unroll
        for (int off = 1; off < 32; off <<= 1) {
            float n = __shfl_up(xacc, off, 64);
            if (tid >= off) xacc += n;
        }
        float L = carryL_in[(size_t)b * NC + c] + xacc;
        rl_sh[tid] = 1.0f / L;
    }
    __syncthreads();

    // prefix stream from LDS, coalesced stores
    if (tid < 128) {
        float* orow = out + ((size_t)b * T + t0) * (size_t)D + tid;
        #pragma unroll
        for (int j = 0; j < CHUNK; ++j) {
            int t = t0 + j;
            if (t >= T) break;
            A += w_sh[j] * vs[j * 128 + tid];
            orow[(size_t)j * D] = A * rl_sh[j];
        }
    }
}

extern "C" void kernel_launch(void* const* d_in, const int* in_sizes, int n_in,
                              void* d_out, int out_size, void* d_ws, size_t ws_size,
                              hipStream_t stream) {
    const float* x        = (const float*)d_in[0];
    const float* Wq       = (const float*)d_in[1];
    const float* Wk       = (const float*)d_in[2];
    const float* Wv       = (const float*)d_in[3];
    const float* kv       = (const float*)d_in[4];
    const int*   next_pos = (const int*)d_in[5];
    float* out = (float*)d_out;

    const int B  = in_sizes[5];                 // 32
    const int E  = in_sizes[0] / B;             // 4096
    const int D  = in_sizes[1] / E;             // 128
    const int T  = out_size / (B * D);          // 1536
    const int MT = in_sizes[4] / (2 * B * D);   // 2048
    const int NC = (T + CHUNK - 1) / CHUNK;     // 48

    float* ws     = (float*)d_ws;
    float* qkv    = ws;                             // 3*B*D
    float* w      = qkv + (size_t)3 * B * D;        // B*T
    float* m      = w + (size_t)B * T;              // B*NC
    float* l      = m + (size_t)B * NC;             // B*NC
    float* acc    = l + (size_t)B * NC;             // B*NC*D
    float* Mc     = acc + (size_t)B * NC * D;       // B*NC
    float* carryL = Mc + (size_t)B * NC;            // B*NC
    float* carryA = carryL + (size_t)B * NC;        // B*NC*D

    const float scale = 1.0f / sqrtf((float)D);

    proj_kernel<<<dim3(D, B), 64, 0, stream>>>(x, Wq, Wk, Wv, qkv, B, E, D);
    score_chunk_kernel<<<dim3(NC, B), 256, 0, stream>>>(kv, qkv, next_pos,
                                                        w, m, l, acc,
                                                        B, D, T, MT, NC, scale);
    size_t scan_lds = ((size_t)NC * 128 + 2 * NC) * sizeof(float);
    scan_kernel<<<dim3(B), 128, scan_lds, stream>>>(m, l, acc, Mc, carryL, carryA,
                                                    B, D, NC);
    out_kernel<<<dim3(NC, B), 256, 0, stream>>>(kv, qkv, next_pos,
                                                w, m, Mc, carryL, carryA, out,
                                                B, D, T, MT, NC);
}